// Round 3
// baseline (1623.657 us; speedup 1.0000x reference)
//
#include <hip/hip_runtime.h>
#include <cstdint>
#include <cstddef>

#define BB  32
#define FF  10
#define NBN 20
#define HH  128
#define GG  5
#define BSTR (FF*NBN*HH)   // 25600
#define FSTR (NBN*HH)      // 2560
#define PADB 36            // [k][b] pad: keeps 16B alignment for float4 reads

struct StageList { int cnt; int cells[20]; };  // packed (r<<16)|(f<<8)|n

__device__ __forceinline__ float sigm(float x) {
  return 1.f / (1.f + __expf(-x));
}
__device__ __forceinline__ float tanh_fast(float x) {
  float e = __expf(-2.f * fabsf(x));
  float t = (1.f - e) / (1.f + e);
  return copysignf(t, x);
}
__device__ __forceinline__ void fma4(float4& a, const float4 w, const float h) {
  a.x = fmaf(w.x, h, a.x); a.y = fmaf(w.y, h, a.y);
  a.z = fmaf(w.z, h, a.z); a.w = fmaf(w.w, h, a.w);
}

// Boundary vectors (pure functions of inputs).
__global__ void precompute_kernel(
    const float* __restrict__ hid, const float* __restrict__ cell,
    const float* __restrict__ gt,
    float* __restrict__ top_c, float* __restrict__ left_c,
    float* __restrict__ top_h0, float* __restrict__ top_h1,
    float* __restrict__ left_h) {
  int idx = blockIdx.x * 256 + threadIdx.x;
  const int NTOP = BB * NBN * HH;
  const int NLEFT = BB * FF * HH;
  if (idx < NTOP) {
    int h = idx & (HH - 1);
    int n = (idx >> 7) % NBN;
    int b = idx / (HH * NBN);
    const float* hp = hid + (size_t)b * BSTR + n * HH + h;
    const float* cp = cell + (size_t)b * BSTR + n * HH + h;
    float sh = 0.f, sc = 0.f;
#pragma unroll
    for (int f = 0; f < FF; ++f) { sh += hp[f * FSTR]; sc += cp[f * FSTR]; }
    top_c[idx]  = sc * (1.f / FF);
    top_h0[idx] = sh * (1.f / FF);
    top_h1[idx] = (sh + gt[idx]) * (1.f / (FF + 1));
  } else if (idx < NTOP + NLEFT) {
    int j = idx - NTOP;
    int h = j & (HH - 1);
    int f = (j >> 7) % FF;
    int b = j / (HH * FF);
    const float* hp = hid + (size_t)b * BSTR + f * FSTR + h;
    const float* cp = cell + (size_t)b * BSTR + f * FSTR + h;
    float sh = 0.f, sc = 0.f;
#pragma unroll
    for (int n = 0; n < NBN; ++n) { sh += hp[n * HH]; sc += cp[n * HH]; }
    left_c[j] = sc * (1.f / NBN);
    left_h[j] = sh * (1.f / NBN);
  }
}

// Z0 = p.U[0] + bias[0] — dependency-free. grid = 200*5, 256 threads.
// Thread: cid = t&31 (4 cols), bq = t>>5 (4 batches) -> 16 acc.
__global__ __launch_bounds__(256)
void z0_kernel(const float* __restrict__ p, const float* __restrict__ U,
               const float* __restrict__ bias, float* __restrict__ Z) {
  __shared__ __align__(16) float xs[HH][PADB];
  const int cell = blockIdx.x / GG, g = blockIdx.x % GG;
  const int f = cell / NBN, n = cell % NBN;
  const int t = threadIdx.x;
  const int cid = t & 31, bq = t >> 5;
  const int cellofs = f * FSTR + n * HH;

  for (int i = t; i < BB * HH; i += 256) {
    int b = i >> 7, k = i & (HH - 1);
    xs[k][b] = p[(size_t)b * BSTR + cellofs + k];
  }
  __syncthreads();

  const float* wu = U + (size_t)cell * (GG * HH * HH) + (size_t)g * HH * HH + cid * 4;
  float4 bv = *(const float4*)(bias + (size_t)cell * (GG * HH) + g * HH + cid * 4);
  float4 acc[4];
#pragma unroll
  for (int j = 0; j < 4; ++j) acc[j] = bv;

#pragma unroll 2
  for (int k = 0; k < HH; ++k) {
    float4 w = *(const float4*)(wu + (size_t)k * HH);
    float4 x = *(const float4*)&xs[k][bq * 4];
    fma4(acc[0], w, x.x); fma4(acc[1], w, x.y);
    fma4(acc[2], w, x.z); fma4(acc[3], w, x.w);
  }

  float* zp = Z + (size_t)cell * (BB * GG * HH) + (size_t)g * HH + cid * 4;
#pragma unroll
  for (int j = 0; j < 4; ++j)
    *(float4*)(zp + (size_t)(bq * 4 + j) * (GG * HH)) = acc[j];
}

// Dependent GEMV for one stage. grid = cnt*5 blocks, 256 threads.
// r=0: Z += ht.Wt + hs.Ws ; r=1: Z = x.U + ht.Wt + hs.Ws + bias
__global__ __launch_bounds__(256)
void gemv_stage(const float* __restrict__ U, const float* __restrict__ Wt,
                const float* __restrict__ Ws, const float* __restrict__ bias,
                const float* __restrict__ h0, const float* __restrict__ out_h,
                const float* __restrict__ top_h0, const float* __restrict__ top_h1,
                const float* __restrict__ left_h,
                float* __restrict__ Z, StageList sl) {
  __shared__ __align__(16) float hts[HH][PADB];  // [k][b]
  __shared__ __align__(16) float hss[HH][PADB];
  __shared__ __align__(16) float xss[HH][PADB];  // r=1 only

  const int cellIdx = blockIdx.x / GG, g = blockIdx.x % GG;
  const int packed = sl.cells[cellIdx];
  const int r = (packed >> 16) & 0xff;
  const int f = (packed >> 8) & 0xff;
  const int n = packed & 0xff;
  const int t = threadIdx.x;
  const int cid = t & 31, bq = t >> 5;
  const int cellofs = f * FSTR + n * HH;

  const float* hbase = r ? out_h : h0;
  const float* hp; int hbs;
  if (f > 0) { hp = hbase + cellofs - FSTR; hbs = BSTR; }
  else       { hp = (r ? top_h1 : top_h0) + n * HH; hbs = FSTR; }
  const float* lp; int lbs;
  if (n > 0) { lp = hbase + cellofs - HH; lbs = BSTR; }
  else       { lp = left_h + f * HH; lbs = FF * HH; }

  for (int i = t; i < BB * HH; i += 256) {
    int b = i >> 7, k = i & (HH - 1);
    hts[k][b] = hp[(size_t)b * hbs + k];
    hss[k][b] = lp[(size_t)b * lbs + k];
    if (r) xss[k][b] = h0[(size_t)b * BSTR + cellofs + k];
  }
  __syncthreads();

  const size_t wofs = ((size_t)(r * FF + f) * NBN + n) * (GG * HH * HH)
                    + (size_t)g * HH * HH + cid * 4;
  const float* wtp = Wt + wofs;
  const float* wsp = Ws + wofs;
  const float* wup = U + wofs;

  float4 acc[4];
  if (r) {
    float4 bv = *(const float4*)(bias + (((size_t)(FF + f) * NBN + n) * GG + g) * HH + cid * 4);
#pragma unroll
    for (int j = 0; j < 4; ++j) acc[j] = bv;
#pragma unroll 2
    for (int k = 0; k < HH; ++k) {
      float4 wt4 = *(const float4*)(wtp + (size_t)k * HH);
      float4 ws4 = *(const float4*)(wsp + (size_t)k * HH);
      float4 wu4 = *(const float4*)(wup + (size_t)k * HH);
      float4 ht4 = *(const float4*)&hts[k][bq * 4];
      float4 hs4 = *(const float4*)&hss[k][bq * 4];
      float4 xx4 = *(const float4*)&xss[k][bq * 4];
      fma4(acc[0], wt4, ht4.x); fma4(acc[1], wt4, ht4.y);
      fma4(acc[2], wt4, ht4.z); fma4(acc[3], wt4, ht4.w);
      fma4(acc[0], ws4, hs4.x); fma4(acc[1], ws4, hs4.y);
      fma4(acc[2], ws4, hs4.z); fma4(acc[3], ws4, hs4.w);
      fma4(acc[0], wu4, xx4.x); fma4(acc[1], wu4, xx4.y);
      fma4(acc[2], wu4, xx4.z); fma4(acc[3], wu4, xx4.w);
    }
  } else {
#pragma unroll
    for (int j = 0; j < 4; ++j) acc[j] = make_float4(0.f, 0.f, 0.f, 0.f);
#pragma unroll 2
    for (int k = 0; k < HH; ++k) {
      float4 wt4 = *(const float4*)(wtp + (size_t)k * HH);
      float4 ws4 = *(const float4*)(wsp + (size_t)k * HH);
      float4 ht4 = *(const float4*)&hts[k][bq * 4];
      float4 hs4 = *(const float4*)&hss[k][bq * 4];
      fma4(acc[0], wt4, ht4.x); fma4(acc[1], wt4, ht4.y);
      fma4(acc[2], wt4, ht4.z); fma4(acc[3], wt4, ht4.w);
      fma4(acc[0], ws4, hs4.x); fma4(acc[1], ws4, hs4.y);
      fma4(acc[2], ws4, hs4.z); fma4(acc[3], ws4, hs4.w);
    }
  }

  float* zp = Z + (size_t)(f * NBN + n) * (BB * GG * HH) + (size_t)g * HH + cid * 4;
  if (r) {
#pragma unroll
    for (int j = 0; j < 4; ++j)
      *(float4*)(zp + (size_t)(bq * 4 + j) * (GG * HH)) = acc[j];
  } else {
#pragma unroll
    for (int j = 0; j < 4; ++j) {
      float4* dst = (float4*)(zp + (size_t)(bq * 4 + j) * (GG * HH));
      float4 old = *dst;
      old.x += acc[j].x; old.y += acc[j].y; old.z += acc[j].z; old.w += acc[j].w;
      *dst = old;
    }
  }
}

// Gate combine for one stage. grid = cnt blocks, 512 threads.
__global__ __launch_bounds__(512)
void combine_stage(const float* __restrict__ Z,
                   const float* __restrict__ top_c, const float* __restrict__ left_c,
                   float* __restrict__ h0, float* __restrict__ c0,
                   float* __restrict__ out_h, float* __restrict__ out_c,
                   StageList sl) {
  const int packed = sl.cells[blockIdx.x];
  const int r = (packed >> 16) & 0xff;
  const int f = (packed >> 8) & 0xff;
  const int n = packed & 0xff;
  const int t = threadIdx.x;
  const int c = t & (HH - 1), bh = t >> 7;  // 4 groups x 8 batches
  const int cellofs = f * FSTR + n * HH;

  float* hout = r ? out_h : h0;
  float* cout = r ? out_c : c0;
  const float* ctp; int ctbs;
  if (f > 0) { ctp = cout + cellofs - FSTR; ctbs = BSTR; }
  else       { ctp = top_c + n * HH; ctbs = FSTR; }
  const float* clp; int clbs;
  if (n > 0) { clp = cout + cellofs - HH; clbs = BSTR; }
  else       { clp = left_c + f * HH; clbs = FF * HH; }

  const float* zp = Z + (size_t)(f * NBN + n) * (BB * GG * HH) + c;
#pragma unroll
  for (int j = 0; j < 8; ++j) {
    const int b = bh * 8 + j;
    const float* zb = zp + (size_t)b * (GG * HH);
    float zi = zb[0], zfs = zb[HH], zft = zb[2 * HH], zo = zb[3 * HH], zc = zb[4 * HH];
    float clv = clp[(size_t)b * clbs + c];
    float ctv = ctp[(size_t)b * ctbs + c];
    float iv = sigm(zi), fsv = sigm(zfs), ftv = sigm(zft), ov = sigm(zo);
    float cn = tanh_fast(zc);
    float cnew = fmaf(iv, cn, fmaf(fsv, clv, ftv * ctv));
    float hnew = ov * tanh_fast(cnew);
    hout[(size_t)b * BSTR + cellofs + c] = hnew;
    cout[(size_t)b * BSTR + cellofs + c] = cnew;
  }
}

extern "C" void kernel_launch(void* const* d_in, const int* in_sizes, int n_in,
                              void* d_out, int out_size, void* d_ws, size_t ws_size,
                              hipStream_t stream) {
  const float* hid  = (const float*)d_in[0];
  const float* cell = (const float*)d_in[1];
  const float* gt   = (const float*)d_in[2];
  // d_in[3] = global_s_state — dead for R=2
  const float* p    = (const float*)d_in[4];
  const float* U    = (const float*)d_in[5];
  const float* Wt   = (const float*)d_in[6];
  const float* Ws   = (const float*)d_in[7];
  const float* bias = (const float*)d_in[8];

  float* out_h = (float*)d_out;
  float* out_c = out_h + (size_t)BB * BSTR;

  float* w = (float*)d_ws;
  float* h0     = w; w += (size_t)BB * BSTR;
  float* c0     = w; w += (size_t)BB * BSTR;
  float* top_c  = w; w += (size_t)BB * NBN * HH;
  float* left_c = w; w += (size_t)BB * FF * HH;
  float* top_h0 = w; w += (size_t)BB * NBN * HH;
  float* top_h1 = w; w += (size_t)BB * NBN * HH;
  float* left_h = w; w += (size_t)BB * FF * HH;
  float* Z      = w; w += (size_t)FF * NBN * BB * GG * HH;  // 16.4 MB

  const int pre_threads = BB * NBN * HH + BB * FF * HH;
  hipLaunchKernelGGL(precompute_kernel, dim3((pre_threads + 255) / 256), dim3(256),
                     0, stream, hid, cell, gt, top_c, left_c, top_h0, top_h1, left_h);

  hipLaunchKernelGGL(z0_kernel, dim3(FF * NBN * GG), dim3(256), 0, stream,
                     p, U, bias, Z);

  for (int d = 0; d < FF + NBN; ++d) {
    StageList sl; sl.cnt = 0;
    for (int r = 0; r < 2; ++r) {
      int dd = d - r;
      for (int f = 0; f < FF; ++f) {
        int n = dd - f;
        if (n >= 0 && n < NBN) sl.cells[sl.cnt++] = (r << 16) | (f << 8) | n;
      }
    }
    if (sl.cnt == 0) continue;
    hipLaunchKernelGGL(gemv_stage, dim3(sl.cnt * GG), dim3(256), 0, stream,
                       U, Wt, Ws, bias, h0, out_h, top_h0, top_h1, left_h, Z, sl);
    hipLaunchKernelGGL(combine_stage, dim3(sl.cnt), dim3(512), 0, stream,
                       Z, top_c, left_c, h0, c0, out_h, out_c, sl);
  }
}